// Round 6
// baseline (229.949 us; speedup 1.0000x reference)
//
#include <hip/hip_runtime.h>
#include <math.h>

// RX gate on qubit 5 of 12, batch 4096 states of dim 4096.
// out_re[i] = c*sr[i] + s*si[i^64];  out_im[i] = c*si[i] - s*sr[i^64]
// (M = c*I - i*s*X_hyd is symmetric; X_hyd is the bit-6 flip permutation.)
//
// v6 (resubmit — round 5 failed on container acquisition, kernel never ran):
// copy-shaped streaming in the NT regime.
//   - NT loads + NT stores (v5's +14us win: bypass L2/L3 alloc churn)
//   - persistent grid-stride: 2048 blocks x 256 th x 8 rounds, wave lives
//     the whole kernel with next round's loads always in flight
//   - lane-linear addressing: vec index = tid + k*2^19, so EVERY global
//     load/store instruction is one contiguous 1KB wave transaction
//     (v2/v5's pair-per-thread forced 4x256B @ stride 512B scatter)
//   - butterfly partner vec = v^16 lives in lane^16 of the same wave ->
//     __shfl_xor(...,16); VALU is ~3% busy, shuffles are free, and the
//     lgkmcnt waits hide under 32 resident waves/CU
// This is the definitive "can source structure reach copy speed" test:
// if it stays at ~66us kernel time, the ~4 TB/s mixed R/W rate is the
// environment's machinery ceiling and we are done.

#define NQ_N 4096
#define NQ_BATCH 4096

typedef float f32x4 __attribute__((ext_vector_type(4)));

#define BLK 256u
#define GRID 2048u
#define RSTRIDE (GRID * BLK)          // 2^19 vecs per round
#define ROUNDS 8u                     // 2^22 total vecs / 2^19

__global__ __launch_bounds__(BLK, 8)
void rx_stream_kernel(const f32x4* __restrict__ sr,
                      const f32x4* __restrict__ si,
                      const float* __restrict__ theta_p,
                      f32x4* __restrict__ out_re,
                      f32x4* __restrict__ out_im)
{
    const float half = 0.5f * theta_p[0];
    const float c = cosf(half);
    const float s = sinf(half);

    const unsigned tid = blockIdx.x * BLK + threadIdx.x;

    // prologue: round-0 loads (lane-linear, 1KB/wave/instruction)
    f32x4 r = __builtin_nontemporal_load(sr + tid);
    f32x4 m = __builtin_nontemporal_load(si + tid);

#pragma unroll
    for (unsigned k = 0; k < ROUNDS; ++k) {
        const unsigned v = tid + k * RSTRIDE;

        // issue next round's loads BEFORE touching this round's data
        f32x4 rn, mn;
        if (k + 1 < ROUNDS) {
            rn = __builtin_nontemporal_load(sr + v + RSTRIDE);
            mn = __builtin_nontemporal_load(si + v + RSTRIDE);
        }

        // partner vec = v ^ 16 -> lane ^ 16 of this wave
        f32x4 rp, mp;
        rp.x = __shfl_xor(r.x, 16);
        rp.y = __shfl_xor(r.y, 16);
        rp.z = __shfl_xor(r.z, 16);
        rp.w = __shfl_xor(r.w, 16);
        mp.x = __shfl_xor(m.x, 16);
        mp.y = __shfl_xor(m.y, 16);
        mp.z = __shfl_xor(m.z, 16);
        mp.w = __shfl_xor(m.w, 16);

        f32x4 ore, oim;
#pragma unroll
        for (int q = 0; q < 4; ++q) {
            ore[q] = fmaf(c, r[q],  s * mp[q]);
            oim[q] = fmaf(c, m[q], -s * rp[q]);
        }

        __builtin_nontemporal_store(ore, out_re + v);
        __builtin_nontemporal_store(oim, out_im + v);

        r = rn;
        m = mn;
    }
}

extern "C" void kernel_launch(void* const* d_in, const int* in_sizes, int n_in,
                              void* d_out, int out_size, void* d_ws, size_t ws_size,
                              hipStream_t stream)
{
    const f32x4* sr = (const f32x4*)d_in[0];
    const f32x4* si = (const f32x4*)d_in[1];
    const float* th = (const float*)d_in[2];

    f32x4* out_re = (f32x4*)d_out;
    f32x4* out_im = out_re + ((size_t)NQ_BATCH * NQ_N / 4);

    rx_stream_kernel<<<GRID, BLK, 0, stream>>>(sr, si, th, out_re, out_im);
}

// Round 7
// 224.538 us; speedup vs baseline: 1.0241x; 1.0241x over previous
//
#include <hip/hip_runtime.h>
#include <math.h>

// RX gate on qubit 5 of 12, batch 4096 states of dim 4096.
// out_re[i] = c*sr[i] + s*si[i^64];  out_im[i] = c*si[i] - s*sr[i^64]
// (M = c*I - i*s*X_hyd is symmetric; X_hyd is the bit-6 flip permutation.)
//
// v7: v5 (best: pair-per-thread, 8 loads in flight, grid 4096, NT stores,
// kernel ~66us) with ONE change: input loads carry full cache-bypass flags
// `sc0 sc1 nt` (system scope) via inline asm -> skip L0/L1 and the per-XCD
// L2 entirely; served at the coherence point (memory-side MALL/HBM, so L3
// hits are retained). Rationale: the ONLY lever that has ever moved this
// kernel is cache-path machinery (nt alloc-bypass: 79.5 -> 66us); structure
// is proven irrelevant (4 shapes all equal). This tests the remaining piece
// of that mechanism: L2 probe/merge occupancy on the read-return path.
// Correctness: inputs are H2D-written once, never re-poisoned -> no dirty
// L2 lines to miss; stores unchanged (NT builtins, harness D2H is coherent).

#define NQ_N 4096
#define NQ_BATCH 4096

typedef float f32x4 __attribute__((ext_vector_type(4)));

// total f32x4 vecs = 4096*4096/4 = 2^22 ; pairs = 2^21 ; 2 pairs/thread
#define TOTAL_PAIRS (1u << 21)
#define PAIR_OFFSET (1u << 20)   // second pair = first + half the pair space

__device__ __forceinline__ f32x4 ld_bypass(const f32x4* __restrict__ base,
                                           unsigned byte_off)
{
    f32x4 dst;
    asm volatile("global_load_dwordx4 %0, %1, %2 sc0 sc1 nt"
                 : "=&v"(dst)
                 : "v"(byte_off), "s"(base)
                 : "memory");
    return dst;
}

__global__ __launch_bounds__(256)
void rx_bypass_kernel(const f32x4* __restrict__ sr,
                      const f32x4* __restrict__ si,
                      const float* __restrict__ theta_p,
                      f32x4* __restrict__ out_re,
                      f32x4* __restrict__ out_im)
{
    const float half = 0.5f * theta_p[0];
    const float c = cosf(half);
    const float s = sinf(half);

    const unsigned u = blockIdx.x * blockDim.x + threadIdx.x; // pair id

    const unsigned p0 = u;
    const unsigned p1 = u + PAIR_OFFSET;

    // pair p -> vec index i with bit4 forced to 0: i = p + (p & ~15)
    const unsigned i0 = p0 + (p0 & ~15u);
    const unsigned j0 = i0 + 16;
    const unsigned i1 = p1 + (p1 & ~15u);
    const unsigned j1 = i1 + 16;

    // byte offsets (max vec index 2^22 -> max offset 2^26, fits 32-bit)
    const unsigned bi0 = i0 * 16u, bj0 = j0 * 16u;
    const unsigned bi1 = i1 * 16u, bj1 = j1 * 16u;

    // 8 independent bypass loads, issued back-to-back (volatile asm keeps
    // program order; addresses are read at issue, dests land at waitcnt)
    const f32x4 rA = ld_bypass(sr, bi0);
    const f32x4 rB = ld_bypass(sr, bj0);
    const f32x4 mA = ld_bypass(si, bi0);
    const f32x4 mB = ld_bypass(si, bj0);
    const f32x4 rC = ld_bypass(sr, bi1);
    const f32x4 rD = ld_bypass(sr, bj1);
    const f32x4 mC = ld_bypass(si, bi1);
    const f32x4 mD = ld_bypass(si, bj1);

    // drain all loads; fence the scheduler so compute can't hoist (rule #18)
    asm volatile("s_waitcnt vmcnt(0)" ::: "memory");
    __builtin_amdgcn_sched_barrier(0);

    f32x4 reA, imA, reB, imB, reC, imC, reD, imD;
#pragma unroll
    for (int k = 0; k < 4; ++k) {
        reA[k] = fmaf(c, rA[k],  s * mB[k]);
        imA[k] = fmaf(c, mA[k], -s * rB[k]);
        reB[k] = fmaf(c, rB[k],  s * mA[k]);
        imB[k] = fmaf(c, mB[k], -s * rA[k]);
        reC[k] = fmaf(c, rC[k],  s * mD[k]);
        imC[k] = fmaf(c, mC[k], -s * rD[k]);
        reD[k] = fmaf(c, rD[k],  s * mC[k]);
        imD[k] = fmaf(c, mD[k], -s * rC[k]);
    }

    __builtin_nontemporal_store(reA, out_re + i0);
    __builtin_nontemporal_store(imA, out_im + i0);
    __builtin_nontemporal_store(reB, out_re + j0);
    __builtin_nontemporal_store(imB, out_im + j0);
    __builtin_nontemporal_store(reC, out_re + i1);
    __builtin_nontemporal_store(imC, out_im + i1);
    __builtin_nontemporal_store(reD, out_re + j1);
    __builtin_nontemporal_store(imD, out_im + j1);
}

extern "C" void kernel_launch(void* const* d_in, const int* in_sizes, int n_in,
                              void* d_out, int out_size, void* d_ws, size_t ws_size,
                              hipStream_t stream)
{
    const f32x4* sr = (const f32x4*)d_in[0];
    const f32x4* si = (const f32x4*)d_in[1];
    const float* th = (const float*)d_in[2];

    f32x4* out_re = (f32x4*)d_out;
    f32x4* out_im = out_re + ((size_t)NQ_BATCH * NQ_N / 4);

    const unsigned threads = TOTAL_PAIRS / 2;  // 2 pairs per thread -> 2^20
    const unsigned block = 256;
    const unsigned grid = threads / block;     // 4096

    rx_bypass_kernel<<<grid, block, 0, stream>>>(sr, si, th, out_re, out_im);
}